// Round 8
// baseline (146.743 us; speedup 1.0000x reference)
//
#include <hip/hip_runtime.h>

// Causal FA fwd: B=2,H=8,S=4096,D=64, fp32 in/out, bf16 MFMA 32x32x16.
// R13: causal q-tile PAIRING for load balance. Old grid 1024 blocks ==
//      exact resident capacity (4/CU): all blocks start at t=0, LPT is
//      useless, per-block work = qt+1 in {1..65} -> worst CU ~2x mean ->
//      fa_fwd 61us vs ~30us balanced (occupancy 30%, MfmaUtil 22 both
//      tail-decayed). New: 512 blocks (16 x 32), block y handles q-tiles
//      {63-y, y}: work = (64-y)+(y+1) = 65 iters for EVERY block. Body,
//      numerics, epilogue identical to R12; extra __syncthreads between
//      halves (kv[] scratch reuse). prep_kv: R12 version (verified).
// R7 base: in-register softmax->PV via v_permlane32_swap_b32 (probed
// direction), p_sh eliminated, bank conflicts == 0.
// Layouts (m74/m101): C/D 32x32: col=lane&31, row=(reg&3)+8*(reg>>2)+4*(lane>>5).
// A: A[m=lane&31][k=(lane>>5)*8+j]. B: B[n=lane&31][k=(lane>>5)*8+j].

typedef __attribute__((ext_vector_type(8)))  short short8;
typedef __attribute__((ext_vector_type(16))) float floatx16;

#define S_LEN 4096
#define D_DIM 64
#define LOG2E 1.44269504088896340736f
#define M8L2  11.541560327111385f      // 8*log2(e): p = exp(s-8)

__device__ __forceinline__ unsigned short f2bf(float f) {
    union { float f; unsigned u; } x; x.f = f;
    unsigned u = x.u;
    u += 0x7fffu + ((u >> 16) & 1u);   // RNE
    return (unsigned short)(u >> 16);
}

__device__ __forceinline__ float fast_exp2(float x) {
    float r;
    asm("v_exp_f32 %0, %1" : "=v"(r) : "v"(x));
    return r;
}

__device__ __forceinline__ void glds16(const void* g, void* l) {
    __builtin_amdgcn_global_load_lds(
        (const __attribute__((address_space(1))) unsigned int*)g,
        (__attribute__((address_space(3))) unsigned int*)l, 16, 0, 0);
}

// Image per (bh, 64-key tile): 16 frag-blocks of 1KB (8192 shorts total).
// Logical granule (f, L):
//  K A-frag f = (key>>5)*4+ks : keys (f>>2)*32+(L&31), d = (f&3)*16+(L>>5)*8+j
//  V B-frag f = 8+nt*4+vks    : d = nt*32+(L&31), key = (f&3)*16+(L>>5)*8+j
// Physical position within frag: pos(f,L) = L ^ ((f&3)<<1) ^ ((L>>3)&3)
// (bijective per f). Granule lives at f*1024 + pos*16 bytes.
__global__ __launch_bounds__(256) void prep_kv(
        const float* __restrict__ K, const float* __restrict__ V,
        unsigned short* __restrict__ img) {
    const int kt = blockIdx.x;            // 64-key tile, 0..63
    const int bh = blockIdx.y;            // 0..15
    const int t  = threadIdx.x;
    const size_t inbase = (size_t)bh * (S_LEN * D_DIM) + (size_t)kt * (64 * D_DIM);
    unsigned short* out = img + ((size_t)bh * 64 + kt) * 8192;
    __shared__ __align__(16) unsigned short tile[8192];    // full 16KB image
    #pragma unroll
    for (int i = 0; i < 2; ++i) {
        const int g   = i * 256 + t;      // 0..511: (key, 8-elem d-granule)
        const int key = g >> 3;
        const int a   = g & 7;
        const int d8  = a * 8;
        // ---- K granule: one b128 LDS write (bank-balanced via swizzle)
        const float* kp = K + inbase + key * 64 + d8;
        const float4 k0 = *(const float4*)kp;
        const float4 k1 = *(const float4*)(kp + 4);
        unsigned short ks8[8] = { f2bf(k0.x), f2bf(k0.y), f2bf(k0.z), f2bf(k0.w),
                                  f2bf(k1.x), f2bf(k1.y), f2bf(k1.z), f2bf(k1.w) };
        const int fk = (key >> 5) * 4 + (a >> 1);
        const int Lk = (a & 1) * 32 + (key & 31);
        const int pk = Lk ^ ((fk & 3) << 1) ^ ((Lk >> 3) & 3);
        *(uint4*)(tile + fk * 512 + pk * 8) = *(const uint4*)ks8;
        // ---- V granule: 8 scalar writes (transpose; ~4-way via swizzle)
        const float* vp = V + inbase + key * 64 + d8;
        const float4 v0 = *(const float4*)vp;
        const float4 v1 = *(const float4*)(vp + 4);
        const float vv[8] = { v0.x, v0.y, v0.z, v0.w, v1.x, v1.y, v1.z, v1.w };
        const int fv = 8 + (a >> 2) * 4 + (key >> 4);
        const int jj = key & 7;
        #pragma unroll
        for (int j = 0; j < 8; ++j) {
            const int Lv = ((key >> 3) & 1) * 32 + 8 * (a & 3) + j;
            const int pv = Lv ^ ((fv & 3) << 1) ^ ((Lv >> 3) & 3);
            tile[fv * 512 + pv * 8 + jj] = f2bf(vv[j]);
        }
    }
    __syncthreads();
    // ---- linear dump of ALL 1024 granules: conflict-free LDS reads,
    // perfectly coalesced global stores
    #pragma unroll
    for (int i = 0; i < 4; ++i) {
        const int o = i * 256 + t;        // granule 0..1023
        *(uint4*)(out + o * 8) = *(const uint4*)(tile + o * 8);
    }
}

__global__ __launch_bounds__(256, 4) void fa_fwd(
        const float* __restrict__ Q, const unsigned short* __restrict__ img,
        float* __restrict__ O) {
    const int bh = blockIdx.x;
    const int by = (int)blockIdx.y;        // 0..31; handles q-tiles {63-by, by}
    const int tid  = threadIdx.x;
    const int wave = tid >> 6;
    const int lane = tid & 63;
    const int l31  = lane & 31;
    const int hl   = lane >> 5;
    const int wq   = wave >> 1;            // q half  (0/1)
    const int wk   = wave & 1;             // key half (0/1)
    const int laneS = lane ^ ((lane >> 3) & 3);   // swizzle base (R11)

    __shared__ __align__(16) unsigned short kv[2][8192];    // double-buffered tile (32KB)

    // ---- probe v_permlane32_swap_b32 direction (wave-uniform result).
    // H1: vdst.lanes[0:31] <-> src.lanes[32:63]  -> r0 = {src.hi->lo, vdst.hi}
    // H2: vdst.lanes[32:63] <-> src.lanes[0:31]  -> r0 = {vdst.lo, src.lo->hi}
    bool h1;
    {
        const unsigned pa = hl ? 0xA1u : 0xA0u;
        const unsigned pb = hl ? 0xB1u : 0xB0u;
        auto pr = __builtin_amdgcn_permlane32_swap(pa, pb, false, false);
        h1 = ((unsigned)pr[0] == (hl ? 0xA1u : 0xB1u));
    }

    const size_t base = (size_t)bh * (S_LEN * D_DIM);
    const unsigned short* tsrc = img + (size_t)bh * 64 * 8192;

    // DMA one 16KB tile: wave handles frag-blocks wave*4 .. wave*4+3
    #define DMA_TILE(KT, BUF)                                                  \
        { const unsigned short* s_ = tsrc + (size_t)(KT) * 8192;               \
          _Pragma("unroll")                                                    \
          for (int i_ = 0; i_ < 4; ++i_) {                                     \
              const int f_ = wave * 4 + i_;                                    \
              glds16(s_ + f_ * 512 + lane * 8, (BUF) + f_ * 512 + lane * 8);   \
          } }

    for (int half = 0; half < 2; ++half) {
        const int qt = half ? by : 63 - by;   // heavy tile first
        const int q0 = qt * 64;
        const int nkt = qt + 1;

        if (half) __syncthreads();            // kv[] scratch from prev epilogue safe

        // Q B-frags (resident), scale 1/8 folded: B[n=q=l31][k=d=ks*16+hl*8+j]
        short8 qf[4];
        {
            const float* qp = Q + base + (size_t)(q0 + wq * 32 + l31) * D_DIM + hl * 8;
            #pragma unroll
            for (int ks = 0; ks < 4; ++ks) {
                const float4 f0 = *(const float4*)(qp + ks * 16);
                const float4 f1 = *(const float4*)(qp + ks * 16 + 4);
                short8 a;
                a[0] = (short)f2bf(f0.x * 0.125f); a[1] = (short)f2bf(f0.y * 0.125f);
                a[2] = (short)f2bf(f0.z * 0.125f); a[3] = (short)f2bf(f0.w * 0.125f);
                a[4] = (short)f2bf(f1.x * 0.125f); a[5] = (short)f2bf(f1.y * 0.125f);
                a[6] = (short)f2bf(f1.z * 0.125f); a[7] = (short)f2bf(f1.w * 0.125f);
                qf[ks] = a;
            }
        }

        floatx16 o_acc[2];
        #pragma unroll
        for (int n = 0; n < 2; ++n)
            #pragma unroll
            for (int r = 0; r < 16; ++r) o_acc[n][r] = 0.f;
        float lsum = 0.f;

        DMA_TILE(0, kv[0])

        for (int kt = 0; kt < nkt; ++kt) {
            asm volatile("s_waitcnt vmcnt(0)" ::: "memory");   // own DMAs for buf[kt&1] landed
            __builtin_amdgcn_s_barrier();                      // all waves landed + prev reads done
            asm volatile("" ::: "memory");
            unsigned short* buf = kv[kt & 1];
            if (kt + 1 < nkt) DMA_TILE(kt + 1, kv[(kt + 1) & 1])   // in flight across compute

            const bool diag = (kt == nkt - 1);
            if (diag && wk > wq) continue;     // fully-masked wave: skip compute (no barriers below)

            // ---- S^T = K·Q^T : rows = 32 keys, cols = 32 q
            floatx16 s;
            #pragma unroll
            for (int r = 0; r < 16; ++r) s[r] = 0.f;
            #pragma unroll
            for (int ks = 0; ks < 4; ++ks) {
                const short8 ak = *(const short8*)&buf[(wk * 4 + ks) * 512 + (laneS ^ (ks << 1)) * 8];
                s = __builtin_amdgcn_mfma_f32_32x32x16_bf16(ak, qf[ks], s, 0, 0, 0);
            }

            // ---- p = exp(s-8), causal mask on diag, lsum
            float p[16];
            #pragma unroll
            for (int r = 0; r < 16; ++r)
                p[r] = fast_exp2(fmaf(s[r], LOG2E, -M8L2));
            if (diag && wk == wq) {
                #pragma unroll
                for (int r = 0; r < 16; ++r) {
                    const int row = (r & 3) + 8 * (r >> 2) + 4 * hl;   // key local
                    p[r] = (row > l31) ? 0.f : p[r];
                }
            }
            #pragma unroll
            for (int r = 0; r < 16; ++r) lsum += p[r];

            // ---- pack pairs to bf16 words: w[rg] = keys {8rg+4hl+0..3} for q=l31
            unsigned w[4][2];
            #pragma unroll
            for (int rg = 0; rg < 4; ++rg) {
                w[rg][0] = __builtin_amdgcn_perm(__float_as_uint(p[rg * 4 + 1]),
                                                 __float_as_uint(p[rg * 4 + 0]), 0x07060302u);
                w[rg][1] = __builtin_amdgcn_perm(__float_as_uint(p[rg * 4 + 3]),
                                                 __float_as_uint(p[rg * 4 + 2]), 0x07060302u);
            }

            // ---- in-register redistribute: A-frag word j holds keys kk*16+hl*8+2j..+1.
            // word0 = {w[rg].lo, w[rg+1].lo^}, word2 = {w[rg].hi^, w[rg+1].hi}
            // (^ = cross-half). One permlane32_swap yields both.
            unsigned a0[4], a1[4];
            if (h1) {
                auto s0 = __builtin_amdgcn_permlane32_swap(w[1][0], w[0][0], false, false);
                a0[2] = (unsigned)s0[0]; a0[0] = (unsigned)s0[1];
                auto s1 = __builtin_amdgcn_permlane32_swap(w[1][1], w[0][1], false, false);
                a0[3] = (unsigned)s1[0]; a0[1] = (unsigned)s1[1];
                auto s2 = __builtin_amdgcn_permlane32_swap(w[3][0], w[2][0], false, false);
                a1[2] = (unsigned)s2[0]; a1[0] = (unsigned)s2[1];
                auto s3 = __builtin_amdgcn_permlane32_swap(w[3][1], w[2][1], false, false);
                a1[3] = (unsigned)s3[0]; a1[1] = (unsigned)s3[1];
            } else {
                auto s0 = __builtin_amdgcn_permlane32_swap(w[0][0], w[1][0], false, false);
                a0[0] = (unsigned)s0[0]; a0[2] = (unsigned)s0[1];
                auto s1 = __builtin_amdgcn_permlane32_swap(w[0][1], w[1][1], false, false);
                a0[1] = (unsigned)s1[0]; a0[3] = (unsigned)s1[1];
                auto s2 = __builtin_amdgcn_permlane32_swap(w[2][0], w[3][0], false, false);
                a1[0] = (unsigned)s2[0]; a1[2] = (unsigned)s2[1];
                auto s3 = __builtin_amdgcn_permlane32_swap(w[2][1], w[3][1], false, false);
                a1[1] = (unsigned)s3[0]; a1[3] = (unsigned)s3[1];
            }
            union Cvt { unsigned u[4]; short8 s8; };
            Cvt c0, c1;
            c0.u[0] = a0[0]; c0.u[1] = a0[1]; c0.u[2] = a0[2]; c0.u[3] = a0[3];
            c1.u[0] = a1[0]; c1.u[1] = a1[1]; c1.u[2] = a1[2]; c1.u[3] = a1[3];
            const short8 apf[2] = { c0.s8, c1.s8 };

            // ---- O += P·V  (P A-frags fully in-register; no LDS round-trip)
            #pragma unroll
            for (int kk = 0; kk < 2; ++kk) {
                #pragma unroll
                for (int nt = 0; nt < 2; ++nt) {
                    const int fv3 = 2 * wk + kk;   // f&3 for this V frag
                    const short8 bv = *(const short8*)&buf[4096 + (nt * 4 + fv3) * 512 + (laneS ^ (fv3 << 1)) * 8];
                    o_acc[nt] = __builtin_amdgcn_mfma_f32_32x32x16_bf16(apf[kk], bv, o_acc[nt], 0, 0, 0);
                }
            }
        }

        // ---- epilogue: fold l across halves; cross-(wk) O/l reduce via LDS
        lsum += __shfl_xor(lsum, 32);          // lane holds full partial for q = l31
        __syncthreads();                       // main loop fully done; kv reusable
        float* ored = (float*)kv[0];           // [wq][q(32)][d(64)] floats = 16KB
        float* lred = (float*)kv[1];           // [wk*2+wq][q] partial row sums (512B)
        if (lane < 32) lred[(wk * 2 + wq) * 32 + lane] = lsum;
        if (wk == 1) {
            #pragma unroll
            for (int nt = 0; nt < 2; ++nt)
                #pragma unroll
                for (int r = 0; r < 16; ++r) {
                    const int q = (r & 3) + 8 * (r >> 2) + 4 * hl;
                    ored[wq * 2048 + q * 64 + nt * 32 + l31] = o_acc[nt][r];
                }
        }
        __syncthreads();
        if (wk == 0) {
            #pragma unroll
            for (int r = 0; r < 16; ++r) {
                const int q = (r & 3) + 8 * (r >> 2) + 4 * hl;
                const float l = lred[wq * 32 + q] + lred[(2 + wq) * 32 + q];
                const float inv = 1.0f / l;
                #pragma unroll
                for (int nt = 0; nt < 2; ++nt) {
                    const float v = (o_acc[nt][r] + ored[wq * 2048 + q * 64 + nt * 32 + l31]) * inv;
                    O[base + (size_t)(q0 + wq * 32 + q) * D_DIM + nt * 32 + l31] = v;
                }
            }
        }
    }
    #undef DMA_TILE
}

extern "C" void kernel_launch(void* const* d_in, const int* in_sizes, int n_in,
                              void* d_out, int out_size, void* d_ws, size_t ws_size,
                              hipStream_t stream) {
    const float* q = (const float*)d_in[0];
    const float* k = (const float*)d_in[1];
    const float* v = (const float*)d_in[2];
    float* o = (float*)d_out;
    (void)in_sizes; (void)n_in; (void)out_size; (void)ws_size;
    unsigned short* img = (unsigned short*)d_ws;   // 16MB frag-order KV images
    hipLaunchKernelGGL(prep_kv, dim3(64, 16), dim3(256), 0, stream, k, v, img);
    hipLaunchKernelGGL(fa_fwd,  dim3(16, 32), dim3(256), 0, stream, q, img, o);
}

// Round 9
// 142.561 us; speedup vs baseline: 1.0293x; 1.0293x over previous
//
#include <hip/hip_runtime.h>

// Causal FA fwd: B=2,H=8,S=4096,D=64, fp32 in/out, bf16 MFMA 32x32x16.
// R14: triple-buffered DMA + counted vmcnt (T4). R13 pairing regressed
//      (2 blocks/CU -> 73us: TLP-starved); reverted to 16x64 grid.
//      Old 2-buf schedule: DMA(kt+1) gets ONE compute phase (~600cy) to
//      cover ~500-900cy latency, then vmcnt(0) drains at every barrier ->
//      ~1100cy stall/iter (VALUBusy 47%, period 2250cy). New: kv[3]
//      (48KB, 3 blocks/CU = measured-equal to 4), prologue issues tiles
//      0+1, iter kt waits vmcnt(4) (tile kt landed, kt+1 in flight;
//      vmcnt(0) only on last iter), issues tile kt+2 AFTER the barrier
//      (barrier(kt) => all waves done reading that buffer slot). Runway
//      = 2 compute phases >= latency. Body/numerics identical to R12.
// R7 base: in-register softmax->PV via v_permlane32_swap_b32 (probed
// direction), p_sh eliminated, bank conflicts == 0.
// Layouts (m74/m101): C/D 32x32: col=lane&31, row=(reg&3)+8*(reg>>2)+4*(lane>>5).
// A: A[m=lane&31][k=(lane>>5)*8+j]. B: B[n=lane&31][k=(lane>>5)*8+j].

typedef __attribute__((ext_vector_type(8)))  short short8;
typedef __attribute__((ext_vector_type(16))) float floatx16;

#define S_LEN 4096
#define D_DIM 64
#define LOG2E 1.44269504088896340736f
#define M8L2  11.541560327111385f      // 8*log2(e): p = exp(s-8)

__device__ __forceinline__ unsigned short f2bf(float f) {
    union { float f; unsigned u; } x; x.f = f;
    unsigned u = x.u;
    u += 0x7fffu + ((u >> 16) & 1u);   // RNE
    return (unsigned short)(u >> 16);
}

__device__ __forceinline__ float fast_exp2(float x) {
    float r;
    asm("v_exp_f32 %0, %1" : "=v"(r) : "v"(x));
    return r;
}

__device__ __forceinline__ void glds16(const void* g, void* l) {
    __builtin_amdgcn_global_load_lds(
        (const __attribute__((address_space(1))) unsigned int*)g,
        (__attribute__((address_space(3))) unsigned int*)l, 16, 0, 0);
}

// Image per (bh, 64-key tile): 16 frag-blocks of 1KB (8192 shorts total).
// Logical granule (f, L):
//  K A-frag f = (key>>5)*4+ks : keys (f>>2)*32+(L&31), d = (f&3)*16+(L>>5)*8+j
//  V B-frag f = 8+nt*4+vks    : d = nt*32+(L&31), key = (f&3)*16+(L>>5)*8+j
// Physical position within frag: pos(f,L) = L ^ ((f&3)<<1) ^ ((L>>3)&3)
// (bijective per f). Granule lives at f*1024 + pos*16 bytes.
__global__ __launch_bounds__(256) void prep_kv(
        const float* __restrict__ K, const float* __restrict__ V,
        unsigned short* __restrict__ img) {
    const int kt = blockIdx.x;            // 64-key tile, 0..63
    const int bh = blockIdx.y;            // 0..15
    const int t  = threadIdx.x;
    const size_t inbase = (size_t)bh * (S_LEN * D_DIM) + (size_t)kt * (64 * D_DIM);
    unsigned short* out = img + ((size_t)bh * 64 + kt) * 8192;
    __shared__ __align__(16) unsigned short tile[8192];    // full 16KB image
    #pragma unroll
    for (int i = 0; i < 2; ++i) {
        const int g   = i * 256 + t;      // 0..511: (key, 8-elem d-granule)
        const int key = g >> 3;
        const int a   = g & 7;
        const int d8  = a * 8;
        // ---- K granule: one b128 LDS write (bank-balanced via swizzle)
        const float* kp = K + inbase + key * 64 + d8;
        const float4 k0 = *(const float4*)kp;
        const float4 k1 = *(const float4*)(kp + 4);
        unsigned short ks8[8] = { f2bf(k0.x), f2bf(k0.y), f2bf(k0.z), f2bf(k0.w),
                                  f2bf(k1.x), f2bf(k1.y), f2bf(k1.z), f2bf(k1.w) };
        const int fk = (key >> 5) * 4 + (a >> 1);
        const int Lk = (a & 1) * 32 + (key & 31);
        const int pk = Lk ^ ((fk & 3) << 1) ^ ((Lk >> 3) & 3);
        *(uint4*)(tile + fk * 512 + pk * 8) = *(const uint4*)ks8;
        // ---- V granule: 8 scalar writes (transpose; ~4-way via swizzle)
        const float* vp = V + inbase + key * 64 + d8;
        const float4 v0 = *(const float4*)vp;
        const float4 v1 = *(const float4*)(vp + 4);
        const float vv[8] = { v0.x, v0.y, v0.z, v0.w, v1.x, v1.y, v1.z, v1.w };
        const int fv = 8 + (a >> 2) * 4 + (key >> 4);
        const int jj = key & 7;
        #pragma unroll
        for (int j = 0; j < 8; ++j) {
            const int Lv = ((key >> 3) & 1) * 32 + 8 * (a & 3) + j;
            const int pv = Lv ^ ((fv & 3) << 1) ^ ((Lv >> 3) & 3);
            tile[fv * 512 + pv * 8 + jj] = f2bf(vv[j]);
        }
    }
    __syncthreads();
    // ---- linear dump of ALL 1024 granules: conflict-free LDS reads,
    // perfectly coalesced global stores
    #pragma unroll
    for (int i = 0; i < 4; ++i) {
        const int o = i * 256 + t;        // granule 0..1023
        *(uint4*)(out + o * 8) = *(const uint4*)(tile + o * 8);
    }
}

__global__ __launch_bounds__(256, 3) void fa_fwd(
        const float* __restrict__ Q, const unsigned short* __restrict__ img,
        float* __restrict__ O) {
    const int bh = blockIdx.x;
    const int qt = 63 - (int)blockIdx.y;   // heavy q-tiles dispatch first (LPT)
    const int tid  = threadIdx.x;
    const int wave = tid >> 6;
    const int lane = tid & 63;
    const int l31  = lane & 31;
    const int hl   = lane >> 5;
    const int wq   = wave >> 1;            // q half  (0/1)
    const int wk   = wave & 1;             // key half (0/1)
    const int laneS = lane ^ ((lane >> 3) & 3);   // swizzle base (R11)

    __shared__ __align__(16) unsigned short kv[3][8192];    // triple-buffered tile (48KB)

    // ---- probe v_permlane32_swap_b32 direction (wave-uniform result).
    // H1: vdst.lanes[0:31] <-> src.lanes[32:63]  -> r0 = {src.hi->lo, vdst.hi}
    // H2: vdst.lanes[32:63] <-> src.lanes[0:31]  -> r0 = {vdst.lo, src.lo->hi}
    bool h1;
    {
        const unsigned pa = hl ? 0xA1u : 0xA0u;
        const unsigned pb = hl ? 0xB1u : 0xB0u;
        auto pr = __builtin_amdgcn_permlane32_swap(pa, pb, false, false);
        h1 = ((unsigned)pr[0] == (hl ? 0xA1u : 0xB1u));
    }

    const size_t base = (size_t)bh * (S_LEN * D_DIM);
    const int q0 = qt * 64;

    // Q B-frags (resident), scale 1/8 folded: B[n=q=l31][k=d=ks*16+hl*8+j]
    short8 qf[4];
    {
        const float* qp = Q + base + (size_t)(q0 + wq * 32 + l31) * D_DIM + hl * 8;
        #pragma unroll
        for (int ks = 0; ks < 4; ++ks) {
            const float4 f0 = *(const float4*)(qp + ks * 16);
            const float4 f1 = *(const float4*)(qp + ks * 16 + 4);
            short8 a;
            a[0] = (short)f2bf(f0.x * 0.125f); a[1] = (short)f2bf(f0.y * 0.125f);
            a[2] = (short)f2bf(f0.z * 0.125f); a[3] = (short)f2bf(f0.w * 0.125f);
            a[4] = (short)f2bf(f1.x * 0.125f); a[5] = (short)f2bf(f1.y * 0.125f);
            a[6] = (short)f2bf(f1.z * 0.125f); a[7] = (short)f2bf(f1.w * 0.125f);
            qf[ks] = a;
        }
    }

    floatx16 o_acc[2];
    #pragma unroll
    for (int n = 0; n < 2; ++n)
        #pragma unroll
        for (int r = 0; r < 16; ++r) o_acc[n][r] = 0.f;
    float lsum = 0.f;

    const unsigned short* tsrc = img + (size_t)bh * 64 * 8192;
    const int nkt = qt + 1;

    // DMA one 16KB tile: wave handles frag-blocks wave*4 .. wave*4+3
    #define DMA_TILE(KT, BUF)                                                  \
        { const unsigned short* s_ = tsrc + (size_t)(KT) * 8192;               \
          _Pragma("unroll")                                                    \
          for (int i_ = 0; i_ < 4; ++i_) {                                     \
              const int f_ = wave * 4 + i_;                                    \
              glds16(s_ + f_ * 512 + lane * 8, (BUF) + f_ * 512 + lane * 8);   \
          } }

    DMA_TILE(0, kv[0])
    if (nkt > 1) DMA_TILE(1, kv[1])

    for (int kt = 0; kt < nkt; ++kt) {
        // counted wait: tile kt landed; tile kt+1 (if any) may stay in flight
        if (kt + 1 < nkt) { asm volatile("s_waitcnt vmcnt(4)" ::: "memory"); }
        else              { asm volatile("s_waitcnt vmcnt(0)" ::: "memory"); }
        __builtin_amdgcn_s_barrier();      // all waves landed + prev reads done
        asm volatile("" ::: "memory");
        unsigned short* buf = kv[kt % 3];
        // issue tile kt+2 into the slot freed by compute(kt-1) (barrier-safe)
        if (kt + 2 < nkt) DMA_TILE(kt + 2, kv[(kt + 2) % 3])

        const bool diag = (kt == nkt - 1);
        if (diag && wk > wq) continue;     // fully-masked wave: skip compute (no barriers below)

        // ---- S^T = K·Q^T : rows = 32 keys, cols = 32 q
        floatx16 s;
        #pragma unroll
        for (int r = 0; r < 16; ++r) s[r] = 0.f;
        #pragma unroll
        for (int ks = 0; ks < 4; ++ks) {
            const short8 ak = *(const short8*)&buf[(wk * 4 + ks) * 512 + (laneS ^ (ks << 1)) * 8];
            s = __builtin_amdgcn_mfma_f32_32x32x16_bf16(ak, qf[ks], s, 0, 0, 0);
        }

        // ---- p = exp(s-8), causal mask on diag, lsum
        float p[16];
        #pragma unroll
        for (int r = 0; r < 16; ++r)
            p[r] = fast_exp2(fmaf(s[r], LOG2E, -M8L2));
        if (diag && wk == wq) {
            #pragma unroll
            for (int r = 0; r < 16; ++r) {
                const int row = (r & 3) + 8 * (r >> 2) + 4 * hl;   // key local
                p[r] = (row > l31) ? 0.f : p[r];
            }
        }
        #pragma unroll
        for (int r = 0; r < 16; ++r) lsum += p[r];

        // ---- pack pairs to bf16 words: w[rg] = keys {8rg+4hl+0..3} for q=l31
        unsigned w[4][2];
        #pragma unroll
        for (int rg = 0; rg < 4; ++rg) {
            w[rg][0] = __builtin_amdgcn_perm(__float_as_uint(p[rg * 4 + 1]),
                                             __float_as_uint(p[rg * 4 + 0]), 0x07060302u);
            w[rg][1] = __builtin_amdgcn_perm(__float_as_uint(p[rg * 4 + 3]),
                                             __float_as_uint(p[rg * 4 + 2]), 0x07060302u);
        }

        // ---- in-register redistribute: A-frag word j holds keys kk*16+hl*8+2j..+1.
        // word0 = {w[rg].lo, w[rg+1].lo^}, word2 = {w[rg].hi^, w[rg+1].hi}
        // (^ = cross-half). One permlane32_swap yields both.
        unsigned a0[4], a1[4];
        if (h1) {
            auto s0 = __builtin_amdgcn_permlane32_swap(w[1][0], w[0][0], false, false);
            a0[2] = (unsigned)s0[0]; a0[0] = (unsigned)s0[1];
            auto s1 = __builtin_amdgcn_permlane32_swap(w[1][1], w[0][1], false, false);
            a0[3] = (unsigned)s1[0]; a0[1] = (unsigned)s1[1];
            auto s2 = __builtin_amdgcn_permlane32_swap(w[3][0], w[2][0], false, false);
            a1[2] = (unsigned)s2[0]; a1[0] = (unsigned)s2[1];
            auto s3 = __builtin_amdgcn_permlane32_swap(w[3][1], w[2][1], false, false);
            a1[3] = (unsigned)s3[0]; a1[1] = (unsigned)s3[1];
        } else {
            auto s0 = __builtin_amdgcn_permlane32_swap(w[0][0], w[1][0], false, false);
            a0[0] = (unsigned)s0[0]; a0[2] = (unsigned)s0[1];
            auto s1 = __builtin_amdgcn_permlane32_swap(w[0][1], w[1][1], false, false);
            a0[1] = (unsigned)s1[0]; a0[3] = (unsigned)s1[1];
            auto s2 = __builtin_amdgcn_permlane32_swap(w[2][0], w[3][0], false, false);
            a1[0] = (unsigned)s2[0]; a1[2] = (unsigned)s2[1];
            auto s3 = __builtin_amdgcn_permlane32_swap(w[2][1], w[3][1], false, false);
            a1[1] = (unsigned)s3[0]; a1[3] = (unsigned)s3[1];
        }
        union Cvt { unsigned u[4]; short8 s8; };
        Cvt c0, c1;
        c0.u[0] = a0[0]; c0.u[1] = a0[1]; c0.u[2] = a0[2]; c0.u[3] = a0[3];
        c1.u[0] = a1[0]; c1.u[1] = a1[1]; c1.u[2] = a1[2]; c1.u[3] = a1[3];
        const short8 apf[2] = { c0.s8, c1.s8 };

        // ---- O += P·V  (P A-frags fully in-register; no LDS round-trip)
        #pragma unroll
        for (int kk = 0; kk < 2; ++kk) {
            #pragma unroll
            for (int nt = 0; nt < 2; ++nt) {
                const int fv3 = 2 * wk + kk;   // f&3 for this V frag
                const short8 bv = *(const short8*)&buf[4096 + (nt * 4 + fv3) * 512 + (laneS ^ (fv3 << 1)) * 8];
                o_acc[nt] = __builtin_amdgcn_mfma_f32_32x32x16_bf16(apf[kk], bv, o_acc[nt], 0, 0, 0);
            }
        }
    }
    #undef DMA_TILE

    // ---- epilogue: fold l across halves; cross-(wk) O/l reduce via LDS
    lsum += __shfl_xor(lsum, 32);          // lane holds full partial for q = l31
    __syncthreads();                       // main loop fully done; kv reusable
    float* ored = (float*)kv[0];           // [wq][q(32)][d(64)] floats = 16KB
    float* lred = (float*)kv[1];           // [wk*2+wq][q] partial row sums (512B)
    if (lane < 32) lred[(wk * 2 + wq) * 32 + lane] = lsum;
    if (wk == 1) {
        #pragma unroll
        for (int nt = 0; nt < 2; ++nt)
            #pragma unroll
            for (int r = 0; r < 16; ++r) {
                const int q = (r & 3) + 8 * (r >> 2) + 4 * hl;
                ored[wq * 2048 + q * 64 + nt * 32 + l31] = o_acc[nt][r];
            }
    }
    __syncthreads();
    if (wk == 0) {
        #pragma unroll
        for (int r = 0; r < 16; ++r) {
            const int q = (r & 3) + 8 * (r >> 2) + 4 * hl;
            const float l = lred[wq * 32 + q] + lred[(2 + wq) * 32 + q];
            const float inv = 1.0f / l;
            #pragma unroll
            for (int nt = 0; nt < 2; ++nt) {
                const float v = (o_acc[nt][r] + ored[wq * 2048 + q * 64 + nt * 32 + l31]) * inv;
                O[base + (size_t)(q0 + wq * 32 + q) * D_DIM + nt * 32 + l31] = v;
            }
        }
    }
}

extern "C" void kernel_launch(void* const* d_in, const int* in_sizes, int n_in,
                              void* d_out, int out_size, void* d_ws, size_t ws_size,
                              hipStream_t stream) {
    const float* q = (const float*)d_in[0];
    const float* k = (const float*)d_in[1];
    const float* v = (const float*)d_in[2];
    float* o = (float*)d_out;
    (void)in_sizes; (void)n_in; (void)out_size; (void)ws_size;
    unsigned short* img = (unsigned short*)d_ws;   // 16MB frag-order KV images
    hipLaunchKernelGGL(prep_kv, dim3(64, 16), dim3(256), 0, stream, k, v, img);
    hipLaunchKernelGGL(fa_fwd,  dim3(16, 64), dim3(256), 0, stream, q, img, o);
}